// Round 1
// baseline (805.534 us; speedup 1.0000x reference)
//
#include <hip/hip_runtime.h>
#include <math.h>

// Problem dims
#define PP 1024
#define QQ 128
#define BB 64
#define HH 1024   // HP == HQ
#define AA 75
#define APAD 80
#define H3 3072

// ws offsets (in floats)
#define OFF_SQ    0L          // Q*B = 8192
#define OFF_AQ    8192L       // 8192
#define OFF_HA0   16384L      // 64*1024
#define OFF_HAW0  81920L      // 64*80
#define OFF_WH    87040L      // 65536*80
#define OFF_S1    5329920L    // 65536
#define OFF_A1    5395456L    // 65536
#define OFF_C     5460992L    // 65536
#define OFF_GI    5526528L    // 64*3072
#define OFF_GH    5723136L    // 64*3072
#define OFF_HA1   5919744L    // 64*1024
#define OFF_HAW1  5985280L    // 64*80

// ---------------------------------------------------------------------------
// Fused GEMM (M x 1024) @ (75 x 1024)^T with epilogue:
//   raw[r][a]  (optionally stored, padded to 80 cols)
//   s[r] = sum_a tanh(raw + haW[b][a]) * vw[a]  (+ bias)   where b = r & 63
// Block: 256 threads, 64 rows. Thread (g=t>>4, l=t&15): rows 4g..4g+3,
// cols l+16j (j=0..4).
// ---------------------------------------------------------------------------
template <bool ADD_HAW, bool STORE_RAW, bool ADD_BIAS>
__global__ __launch_bounds__(256) void gemm_attn(
    const float* __restrict__ X,    // (M, 1024)
    const float* __restrict__ W,    // (75, 1024)
    const float* __restrict__ haW,  // (64, 80) padded, or nullptr
    const float* __restrict__ vw,   // (75)
    const float* __restrict__ bias, // (1) or nullptr
    float* __restrict__ raw_out,    // (M, 80) or nullptr
    float* __restrict__ s_out)      // (M)
{
    __shared__ float As[64][65];    // [row][k], pad stride 65
    __shared__ float Bs[64][81];    // [k][a],   pad stride 81

    const int t = threadIdx.x;
    const int row0 = blockIdx.x * 64;
    const int l = t & 15;
    const int rbase = (t >> 4) * 4;

    float acc[4][5];
#pragma unroll
    for (int i = 0; i < 4; i++)
#pragma unroll
        for (int j = 0; j < 5; j++) acc[i][j] = 0.f;

    for (int k0 = 0; k0 < 1024; k0 += 64) {
        __syncthreads();
        // Load A tile: 64 rows x 64 k = 1024 float4 slots
#pragma unroll
        for (int i = 0; i < 4; i++) {
            int s = t + i * 256;
            int row = s >> 4, k4 = s & 15;
            const float4 x = *reinterpret_cast<const float4*>(
                X + (row0 + row) * 1024 + k0 + k4 * 4);
            As[row][k4 * 4 + 0] = x.x;
            As[row][k4 * 4 + 1] = x.y;
            As[row][k4 * 4 + 2] = x.z;
            As[row][k4 * 4 + 3] = x.w;
        }
        // Load B tile transposed: 80 a x 16 k4 = 1280 slots
#pragma unroll
        for (int i = 0; i < 5; i++) {
            int s = t + i * 256;
            int a = s >> 4, k4 = s & 15;
            float4 w = make_float4(0.f, 0.f, 0.f, 0.f);
            if (a < AA)
                w = *reinterpret_cast<const float4*>(W + a * 1024 + k0 + k4 * 4);
            Bs[k4 * 4 + 0][a] = w.x;
            Bs[k4 * 4 + 1][a] = w.y;
            Bs[k4 * 4 + 2][a] = w.z;
            Bs[k4 * 4 + 3][a] = w.w;
        }
        __syncthreads();

#pragma unroll 8
        for (int kk = 0; kk < 64; kk++) {
            float av[4], bv[5];
#pragma unroll
            for (int i = 0; i < 4; i++) av[i] = As[rbase + i][kk];
#pragma unroll
            for (int j = 0; j < 5; j++) bv[j] = Bs[kk][l + 16 * j];
#pragma unroll
            for (int i = 0; i < 4; i++)
#pragma unroll
                for (int j = 0; j < 5; j++) acc[i][j] += av[i] * bv[j];
        }
    }

    // Epilogue
#pragma unroll
    for (int i = 0; i < 4; i++) {
        const int r = row0 + rbase + i;
        const int b = r & 63;
        float partial = 0.f;
#pragma unroll
        for (int j = 0; j < 5; j++) {
            const int col = l + 16 * j;
            const float raw = acc[i][j];
            if (STORE_RAW) raw_out[(long)r * APAD + col] = raw;
            if (col < AA) {
                float hw = 0.f;
                if (ADD_HAW) hw = haW[b * APAD + col];
                partial += vw[col] * tanhf(raw + hw);
            }
        }
        partial += __shfl_xor(partial, 1);
        partial += __shfl_xor(partial, 2);
        partial += __shfl_xor(partial, 4);
        partial += __shfl_xor(partial, 8);
        if (l == 0) {
            float res = partial;
            if (ADD_BIAS) res += bias[0];
            s_out[r] = res;
        }
    }
}

// ---------------------------------------------------------------------------
// Softmax over q (axis 0) of s_q (Q=128, B=64): one block per b, 128 threads
// ---------------------------------------------------------------------------
__global__ __launch_bounds__(128) void softmax_q(const float* __restrict__ sq,
                                                 float* __restrict__ aq) {
    const int b = blockIdx.x;
    const int q = threadIdx.x;
    __shared__ float red[2], red2[2];
    float v = sq[q * BB + b];
    float m = v;
#pragma unroll
    for (int off = 1; off < 64; off <<= 1) m = fmaxf(m, __shfl_xor(m, off));
    if ((q & 63) == 0) red[q >> 6] = m;
    __syncthreads();
    m = fmaxf(red[0], red[1]);
    float e = expf(v - m);
    float s = e;
#pragma unroll
    for (int off = 1; off < 64; off <<= 1) s += __shfl_xor(s, off);
    if ((q & 63) == 0) red2[q >> 6] = s;
    __syncthreads();
    s = red2[0] + red2[1];
    aq[q * BB + b] = e / s;
}

// ---------------------------------------------------------------------------
// ha0[b][h] = sum_q aq[q][b] * u[q][b][h].  grid (HH/256, BB), 256 thr
// ---------------------------------------------------------------------------
__global__ __launch_bounds__(256) void pool_q(const float* __restrict__ u,
                                              const float* __restrict__ aq,
                                              float* __restrict__ ha0) {
    const int b = blockIdx.y;
    const int h = blockIdx.x * 256 + threadIdx.x;
    __shared__ float aw[QQ];
    if (threadIdx.x < QQ) aw[threadIdx.x] = aq[threadIdx.x * BB + b];
    __syncthreads();
    float acc = 0.f;
#pragma unroll 4
    for (int q = 0; q < QQ; q++)
        acc += aw[q] * u[(q * BB + b) * HH + h];
    ha0[b * HH + h] = acc;
}

// ---------------------------------------------------------------------------
// out[b][a] = sum_h x[b][h] * W[a][h].  grid (AA, BB), 64 threads
// ---------------------------------------------------------------------------
__global__ __launch_bounds__(64) void vecmat(const float* __restrict__ x,
                                             const float* __restrict__ W,
                                             float* __restrict__ out) {
    const int a = blockIdx.x, b = blockIdx.y, l = threadIdx.x;
    float s = 0.f;
#pragma unroll 4
    for (int k = l; k < HH; k += 64) s += x[b * HH + k] * W[a * HH + k];
#pragma unroll
    for (int off = 1; off < 64; off <<= 1) s += __shfl_xor(s, off);
    if (l == 0) out[b * APAD + a] = s;
}

// ---------------------------------------------------------------------------
// Softmax over p of s1 (P=1024, B=64) + write start logits.
// One block per b, 256 threads x 4 p each.
// ---------------------------------------------------------------------------
__global__ __launch_bounds__(256) void softmax_p(const float* __restrict__ s1,
                                                 float* __restrict__ a1,
                                                 float* __restrict__ outStart) {
    const int b = blockIdx.x;
    const int t = threadIdx.x;
    __shared__ float r4[4], r4b[4];
    float v[4];
    float m = -1e30f;
#pragma unroll
    for (int i = 0; i < 4; i++) {
        const int p = t + i * 256;
        v[i] = s1[p * BB + b];
        outStart[b * PP + p] = v[i];
        m = fmaxf(m, v[i]);
    }
#pragma unroll
    for (int off = 1; off < 64; off <<= 1) m = fmaxf(m, __shfl_xor(m, off));
    if ((t & 63) == 0) r4[t >> 6] = m;
    __syncthreads();
    m = fmaxf(fmaxf(r4[0], r4[1]), fmaxf(r4[2], r4[3]));
    float e[4];
    float s = 0.f;
#pragma unroll
    for (int i = 0; i < 4; i++) {
        e[i] = expf(v[i] - m);
        s += e[i];
    }
#pragma unroll
    for (int off = 1; off < 64; off <<= 1) s += __shfl_xor(s, off);
    if ((t & 63) == 0) r4b[t >> 6] = s;
    __syncthreads();
    s = r4b[0] + r4b[1] + r4b[2] + r4b[3];
    const float inv = 1.f / s;
#pragma unroll
    for (int i = 0; i < 4; i++) a1[(t + i * 256) * BB + b] = e[i] * inv;
}

// ---------------------------------------------------------------------------
// c[b][h] += sum_{p in seg} a1[p][b] * hp[p][b][h].  grid (HH/256, BB, 8)
// ---------------------------------------------------------------------------
__global__ __launch_bounds__(256) void weighted_pool_p(
    const float* __restrict__ hp, const float* __restrict__ a1,
    float* __restrict__ c) {
    const int b = blockIdx.y;
    const int h = blockIdx.x * 256 + threadIdx.x;
    const int ps = blockIdx.z;
    __shared__ float aw[128];
    if (threadIdx.x < 128) aw[threadIdx.x] = a1[(ps * 128 + threadIdx.x) * BB + b];
    __syncthreads();
    float acc = 0.f;
    const long base = ((long)ps * 128 * BB + b) * HH + h;
#pragma unroll 4
    for (int p = 0; p < 128; p++)
        acc += aw[p] * hp[base + (long)p * (BB * HH)];
    atomicAdd(&c[b * HH + h], acc);
}

// ---------------------------------------------------------------------------
// GRU gemms: gi = c @ W_ih^T, gh = ha0 @ W_hh^T.  (64 x 3072, K=1024)
// grid (3072/64, 2), 256 threads; thread (tm=t>>4 rows, tn=t&15 cols) 4x4.
// ---------------------------------------------------------------------------
__global__ __launch_bounds__(256) void gru_gemm(
    const float* __restrict__ c, const float* __restrict__ ha0,
    const float* __restrict__ W_ih, const float* __restrict__ W_hh,
    float* __restrict__ gi, float* __restrict__ gh) {
    const float* X = blockIdx.y ? ha0 : c;
    const float* W = blockIdx.y ? W_hh : W_ih;
    float* out = blockIdx.y ? gh : gi;
    const int n0 = blockIdx.x * 64;
    __shared__ float As[64][65], Ws[64][65];
    const int t = threadIdx.x;
    const int tm = t >> 4, tn = t & 15;
    float acc[4][4];
#pragma unroll
    for (int i = 0; i < 4; i++)
#pragma unroll
        for (int j = 0; j < 4; j++) acc[i][j] = 0.f;

    for (int k0 = 0; k0 < 1024; k0 += 64) {
        __syncthreads();
#pragma unroll
        for (int i = 0; i < 4; i++) {
            int s = t + i * 256;
            int r = s >> 4, k4 = s & 15;
            const float4 x =
                *reinterpret_cast<const float4*>(X + r * 1024 + k0 + k4 * 4);
            As[r][k4 * 4 + 0] = x.x;
            As[r][k4 * 4 + 1] = x.y;
            As[r][k4 * 4 + 2] = x.z;
            As[r][k4 * 4 + 3] = x.w;
            const float4 w = *reinterpret_cast<const float4*>(
                W + (n0 + r) * 1024 + k0 + k4 * 4);
            Ws[r][k4 * 4 + 0] = w.x;
            Ws[r][k4 * 4 + 1] = w.y;
            Ws[r][k4 * 4 + 2] = w.z;
            Ws[r][k4 * 4 + 3] = w.w;
        }
        __syncthreads();
#pragma unroll 8
        for (int kk = 0; kk < 64; kk++) {
            float a[4], wv[4];
#pragma unroll
            for (int i = 0; i < 4; i++) a[i] = As[4 * tm + i][kk];
#pragma unroll
            for (int j = 0; j < 4; j++) wv[j] = Ws[4 * tn + j][kk];
#pragma unroll
            for (int i = 0; i < 4; i++)
#pragma unroll
                for (int j = 0; j < 4; j++) acc[i][j] += a[i] * wv[j];
        }
    }
#pragma unroll
    for (int i = 0; i < 4; i++)
#pragma unroll
        for (int j = 0; j < 4; j++)
            out[(4 * tm + i) * H3 + n0 + 4 * tn + j] = acc[i][j];
}

// ---------------------------------------------------------------------------
// GRU gates: torch GRUCell order [r, z, n], no bias.  grid (HH/256, BB)
// ---------------------------------------------------------------------------
__global__ __launch_bounds__(256) void gru_gate(const float* __restrict__ gi,
                                                const float* __restrict__ gh,
                                                const float* __restrict__ ha0,
                                                float* __restrict__ ha1) {
    const int b = blockIdx.y;
    const int hn = blockIdx.x * 256 + threadIdx.x;
    const long o = (long)b * H3 + hn;
    const float r = 1.f / (1.f + expf(-(gi[o] + gh[o])));
    const float z = 1.f / (1.f + expf(-(gi[o + 1024] + gh[o + 1024])));
    const float n = tanhf(gi[o + 2048] + r * gh[o + 2048]);
    ha1[b * HH + hn] = (1.f - z) * n + z * ha0[b * HH + hn];
}

// ---------------------------------------------------------------------------
// end logits: s2[p][b] = sum_a tanh(Wh[r][a] + haW1[b][a]) * vw[a]
// out[B*P + b*P + p].  grid (65536/64), 256 threads, same layout as gemm epi.
// ---------------------------------------------------------------------------
__global__ __launch_bounds__(256) void end_logits_k(
    const float* __restrict__ wh, const float* __restrict__ haW1,
    const float* __restrict__ vw, float* __restrict__ out) {
    const int row0 = blockIdx.x * 64;
    const int t = threadIdx.x;
    const int l = t & 15;
    const int rbase = (t >> 4) * 4;
#pragma unroll
    for (int i = 0; i < 4; i++) {
        const int r = row0 + rbase + i;
        const int b = r & 63;
        float partial = 0.f;
#pragma unroll
        for (int j = 0; j < 5; j++) {
            const int col = l + 16 * j;
            if (col < AA)
                partial +=
                    vw[col] * tanhf(wh[(long)r * APAD + col] + haW1[b * APAD + col]);
        }
        partial += __shfl_xor(partial, 1);
        partial += __shfl_xor(partial, 2);
        partial += __shfl_xor(partial, 4);
        partial += __shfl_xor(partial, 8);
        if (l == 0) {
            const int p = r >> 6;
            out[(long)BB * PP + b * PP + p] = partial;
        }
    }
}

extern "C" void kernel_launch(void* const* d_in, const int* in_sizes, int n_in,
                              void* d_out, int out_size, void* d_ws,
                              size_t ws_size, hipStream_t stream) {
    const float* hp   = (const float*)d_in[0];  // (P,B,HP)
    const float* u    = (const float*)d_in[1];  // (Q,B,HQ)
    const float* Whp  = (const float*)d_in[2];  // (A,HP)
    const float* Wha  = (const float*)d_in[3];  // (A,HQ)
    const float* v_w  = (const float*)d_in[4];  // (1,A)
    const float* Wuq  = (const float*)d_in[5];  // (A,HQ)
    const float* v1w  = (const float*)d_in[6];  // (1,A)
    const float* v1b  = (const float*)d_in[7];  // (1,)
    const float* W_ih = (const float*)d_in[8];  // (3H,HP)
    const float* W_hh = (const float*)d_in[9];  // (3H,HQ)
    float* out = (float*)d_out;
    float* ws = (float*)d_ws;

    // 1. s_q = tanh(U @ Wuq^T) @ v1 + b1    (M = Q*B = 8192)
    hipLaunchKernelGGL((gemm_attn<false, false, true>), dim3(QQ * BB / 64),
                       dim3(256), 0, stream, u, Wuq, nullptr, v1w, v1b, nullptr,
                       ws + OFF_SQ);
    // 2. softmax over q
    hipLaunchKernelGGL(softmax_q, dim3(BB), dim3(128), 0, stream, ws + OFF_SQ,
                       ws + OFF_AQ);
    // 3. ha0 = sum_q a_q * u
    hipLaunchKernelGGL(pool_q, dim3(HH / 256, BB), dim3(256), 0, stream, u,
                       ws + OFF_AQ, ws + OFF_HA0);
    // 4. haW0 = ha0 @ Wha^T
    hipLaunchKernelGGL(vecmat, dim3(AA, BB), dim3(64), 0, stream, ws + OFF_HA0,
                       Wha, ws + OFF_HAW0);
    // 5. Wh GEMM + s1 epilogue (M = P*B = 65536), stores raw Wh
    hipLaunchKernelGGL((gemm_attn<true, true, false>), dim3(PP * BB / 64),
                       dim3(256), 0, stream, hp, Whp, ws + OFF_HAW0, v_w,
                       nullptr, ws + OFF_WH, ws + OFF_S1);
    // 6. softmax over p + start logits
    hipLaunchKernelGGL(softmax_p, dim3(BB), dim3(256), 0, stream, ws + OFF_S1,
                       ws + OFF_A1, out);
    // 7. c = sum_p a1 * h_passage  (zero + atomic partial sums)
    hipMemsetAsync(ws + OFF_C, 0, (size_t)BB * HH * sizeof(float), stream);
    hipLaunchKernelGGL(weighted_pool_p, dim3(HH / 256, BB, 8), dim3(256), 0,
                       stream, hp, ws + OFF_A1, ws + OFF_C);
    // 8. GRU gemms + gates
    hipLaunchKernelGGL(gru_gemm, dim3(H3 / 64, 2), dim3(256), 0, stream,
                       ws + OFF_C, ws + OFF_HA0, W_ih, W_hh, ws + OFF_GI,
                       ws + OFF_GH);
    hipLaunchKernelGGL(gru_gate, dim3(HH / 256, BB), dim3(256), 0, stream,
                       ws + OFF_GI, ws + OFF_GH, ws + OFF_HA0, ws + OFF_HA1);
    // 9. haW1 = ha1 @ Wha^T
    hipLaunchKernelGGL(vecmat, dim3(AA, BB), dim3(64), 0, stream, ws + OFF_HA1,
                       Wha, ws + OFF_HAW1);
    // 10. end logits from stored Wh
    hipLaunchKernelGGL(end_logits_k, dim3(PP * BB / 64), dim3(256), 0, stream,
                       ws + OFF_WH, ws + OFF_HAW1, v_w, out);
    (void)in_sizes; (void)n_in; (void)out_size; (void)ws_size;
}

// Round 4
// 718.573 us; speedup vs baseline: 1.1210x; 1.1210x over previous
//
#include <hip/hip_runtime.h>
#include <math.h>

// Problem dims
#define PP 1024
#define QQ 128
#define BB 64
#define HH 1024   // HP == HQ
#define AA 75
#define APAD 80
#define H3 3072
#define LDA 40    // bf16 LDS row stride (80 B) -> conflict-free b128 frag reads

// ws offsets (in floats)
#define OFF_SQ    0L          // Q*B = 8192
#define OFF_AQ    8192L       // 8192
#define OFF_HA0   16384L      // 64*1024
#define OFF_HAW0  81920L      // 64*80
#define OFF_WH    87040L      // 65536*80
#define OFF_S1    5329920L    // 65536
#define OFF_A1    5395456L    // 65536
#define OFF_C     5460992L    // 65536
#define OFF_GI    5526528L    // 64*3072
#define OFF_GH    5723136L    // 64*3072
#define OFF_HA1   5919744L    // 64*1024
#define OFF_HAW1  5985280L    // 64*80

typedef __attribute__((ext_vector_type(8))) __bf16 bf16x8;
typedef __attribute__((ext_vector_type(8))) unsigned short ushort8;
typedef __attribute__((ext_vector_type(4))) float f32x4;

__device__ __forceinline__ unsigned short f2bf(float x) {
    unsigned int u = __builtin_bit_cast(unsigned int, x);
    u += 0x7FFFu + ((u >> 16) & 1u);   // RNE
    return (unsigned short)(u >> 16);
}
__device__ __forceinline__ float bf2f(unsigned short h) {
    unsigned int u = ((unsigned int)h) << 16;
    return __builtin_bit_cast(float, u);
}
__device__ __forceinline__ f32x4 mfma16(ushort8 a, ushort8 b, f32x4 c) {
    return __builtin_amdgcn_mfma_f32_16x16x32_bf16(
        __builtin_bit_cast(bf16x8, a), __builtin_bit_cast(bf16x8, b), c, 0, 0, 0);
}
__device__ __forceinline__ void split_store(unsigned short* hi, unsigned short* lo,
                                            int idx, float4 x) {
    ushort4 h, l;
    h.x = f2bf(x.x); l.x = f2bf(x.x - bf2f(h.x));
    h.y = f2bf(x.y); l.y = f2bf(x.y - bf2f(h.y));
    h.z = f2bf(x.z); l.z = f2bf(x.z - bf2f(h.z));
    h.w = f2bf(x.w); l.w = f2bf(x.w - bf2f(h.w));
    *reinterpret_cast<ushort4*>(hi + idx) = h;
    *reinterpret_cast<ushort4*>(lo + idx) = l;
}

// ---------------------------------------------------------------------------
// MFMA GEMM (M x 1024) @ (75 x 1024)^T, split-bf16 (3 mfma / tile), epilogue:
//   raw[r][a] optionally stored (padded 80 cols)
//   s[r] = sum_a tanh(raw + haW[b][a]) * vw[a] (+bias),  b = r & 63
// Block 256 thr = 4 waves; M_BLK=128 (wave w -> rows w*32..w*32+31); N=80.
// ---------------------------------------------------------------------------
template <bool ADD_HAW, bool STORE_RAW, bool ADD_BIAS>
__global__ __launch_bounds__(256) void gemm_attn(
    const float* __restrict__ X,    // (M, 1024)
    const float* __restrict__ W,    // (75, 1024)
    const float* __restrict__ haW,  // (64, 80) padded, or nullptr
    const float* __restrict__ vw,   // (75)
    const float* __restrict__ bias, // (1) or nullptr
    float* __restrict__ raw_out,    // (M, 80) or nullptr
    float* __restrict__ s_out)      // (M)
{
    __shared__ unsigned short Ah[128 * LDA], Al[128 * LDA];
    __shared__ unsigned short Bh[80 * LDA],  Bl[80 * LDA];

    const int t = threadIdx.x;
    const int row0 = blockIdx.x * 128;
    const int w = t >> 6;          // wave
    const int l = t & 63;
    const int lr = l & 15;         // frag row/col
    const int lg = l >> 4;         // frag k-group

    float vwv[5];
#pragma unroll
    for (int nt = 0; nt < 5; nt++) {
        const int col = lr + 16 * nt;
        vwv[nt] = (col < AA) ? vw[col] : 0.f;
    }

    f32x4 acc[2][5];
#pragma unroll
    for (int mt = 0; mt < 2; mt++)
#pragma unroll
        for (int nt = 0; nt < 5; nt++) acc[mt][nt] = (f32x4){0.f, 0.f, 0.f, 0.f};

    for (int k0 = 0; k0 < 1024; k0 += 32) {
        __syncthreads();
        // stage X tile: 128 rows x 32 k (fp32 -> bf16 hi/lo)
#pragma unroll
        for (int i = 0; i < 4; i++) {
            const int s = t + i * 256;           // 0..1023
            const int row = s >> 3, kq = s & 7;
            const float4 x = *reinterpret_cast<const float4*>(
                X + (size_t)(row0 + row) * 1024 + k0 + kq * 4);
            split_store(Ah, Al, row * LDA + kq * 4, x);
        }
        // stage W tile transposed-as-rows: 80 a x 32 k (zeros for a>=75)
#pragma unroll
        for (int i = 0; i < 3; i++) {
            const int s = t + i * 256;
            if (s < 640) {
                const int a = s >> 3, kq = s & 7;
                float4 wv = make_float4(0.f, 0.f, 0.f, 0.f);
                if (a < AA)
                    wv = *reinterpret_cast<const float4*>(W + (size_t)a * 1024 + k0 + kq * 4);
                split_store(Bh, Bl, a * LDA + kq * 4, wv);
            }
        }
        __syncthreads();

        ushort8 ahm[2], alm[2];
#pragma unroll
        for (int mt = 0; mt < 2; mt++) {
            const int ar = (w * 32 + mt * 16 + lr) * LDA + lg * 8;
            ahm[mt] = *reinterpret_cast<const ushort8*>(&Ah[ar]);
            alm[mt] = *reinterpret_cast<const ushort8*>(&Al[ar]);
        }
#pragma unroll
        for (int nt = 0; nt < 5; nt++) {
            const int br = (nt * 16 + lr) * LDA + lg * 8;
            const ushort8 bh = *reinterpret_cast<const ushort8*>(&Bh[br]);
            const ushort8 bl = *reinterpret_cast<const ushort8*>(&Bl[br]);
#pragma unroll
            for (int mt = 0; mt < 2; mt++) {
                acc[mt][nt] = mfma16(ahm[mt], bh, acc[mt][nt]);
                acc[mt][nt] = mfma16(ahm[mt], bl, acc[mt][nt]);
                acc[mt][nt] = mfma16(alm[mt], bh, acc[mt][nt]);
            }
        }
    }

    // Epilogue: D mapping col = lane&15, row = (lane>>4)*4 + reg
#pragma unroll
    for (int mt = 0; mt < 2; mt++) {
#pragma unroll
        for (int r = 0; r < 4; r++) {
            const int row_local = w * 32 + mt * 16 + lg * 4 + r;
            const int rg = row0 + row_local;
            const int b = rg & 63;
            float partial = 0.f;
#pragma unroll
            for (int nt = 0; nt < 5; nt++) {
                const int col = lr + 16 * nt;
                const float v = acc[mt][nt][r];
                if (STORE_RAW) raw_out[(size_t)rg * APAD + col] = v;
                if (col < AA) {
                    float hw = 0.f;
                    if (ADD_HAW) hw = haW[b * APAD + col];
                    partial += vwv[nt] * tanhf(v + hw);
                }
            }
            partial += __shfl_xor(partial, 1);
            partial += __shfl_xor(partial, 2);
            partial += __shfl_xor(partial, 4);
            partial += __shfl_xor(partial, 8);
            if (lr == 0) {
                if (ADD_BIAS) partial += bias[0];
                s_out[rg] = partial;
            }
        }
    }
}

// ---------------------------------------------------------------------------
// Softmax over q (axis 0) of s_q (Q=128, B=64): one block per b, 128 threads
// ---------------------------------------------------------------------------
__global__ __launch_bounds__(128) void softmax_q(const float* __restrict__ sq,
                                                 float* __restrict__ aq) {
    const int b = blockIdx.x;
    const int q = threadIdx.x;
    __shared__ float red[2], red2[2];
    float v = sq[q * BB + b];
    float m = v;
#pragma unroll
    for (int off = 1; off < 64; off <<= 1) m = fmaxf(m, __shfl_xor(m, off));
    if ((q & 63) == 0) red[q >> 6] = m;
    __syncthreads();
    m = fmaxf(red[0], red[1]);
    float e = expf(v - m);
    float s = e;
#pragma unroll
    for (int off = 1; off < 64; off <<= 1) s += __shfl_xor(s, off);
    if ((q & 63) == 0) red2[q >> 6] = s;
    __syncthreads();
    s = red2[0] + red2[1];
    aq[q * BB + b] = e / s;
}

// ---------------------------------------------------------------------------
// ha0[b][h] = sum_q aq[q][b] * u[q][b][h].  grid (HH/256, BB), 256 thr
// ---------------------------------------------------------------------------
__global__ __launch_bounds__(256) void pool_q(const float* __restrict__ u,
                                              const float* __restrict__ aq,
                                              float* __restrict__ ha0) {
    const int b = blockIdx.y;
    const int h = blockIdx.x * 256 + threadIdx.x;
    __shared__ float aw[QQ];
    if (threadIdx.x < QQ) aw[threadIdx.x] = aq[threadIdx.x * BB + b];
    __syncthreads();
    float acc = 0.f;
#pragma unroll 4
    for (int q = 0; q < QQ; q++)
        acc += aw[q] * u[(q * BB + b) * HH + h];
    ha0[b * HH + h] = acc;
}

// ---------------------------------------------------------------------------
// out[b][a] = sum_h x[b][h] * W[a][h].  grid (AA, BB), 64 threads
// ---------------------------------------------------------------------------
__global__ __launch_bounds__(64) void vecmat(const float* __restrict__ x,
                                             const float* __restrict__ W,
                                             float* __restrict__ out) {
    const int a = blockIdx.x, b = blockIdx.y, l = threadIdx.x;
    float s = 0.f;
#pragma unroll 4
    for (int k = l; k < HH; k += 64) s += x[b * HH + k] * W[a * HH + k];
#pragma unroll
    for (int off = 1; off < 64; off <<= 1) s += __shfl_xor(s, off);
    if (l == 0) out[b * APAD + a] = s;
}

// ---------------------------------------------------------------------------
// Softmax over p of s1 (P=1024, B=64) + write start logits.
// ---------------------------------------------------------------------------
__global__ __launch_bounds__(256) void softmax_p(const float* __restrict__ s1,
                                                 float* __restrict__ a1,
                                                 float* __restrict__ outStart) {
    const int b = blockIdx.x;
    const int t = threadIdx.x;
    __shared__ float r4[4], r4b[4];
    float v[4];
    float m = -1e30f;
#pragma unroll
    for (int i = 0; i < 4; i++) {
        const int p = t + i * 256;
        v[i] = s1[p * BB + b];
        outStart[b * PP + p] = v[i];
        m = fmaxf(m, v[i]);
    }
#pragma unroll
    for (int off = 1; off < 64; off <<= 1) m = fmaxf(m, __shfl_xor(m, off));
    if ((t & 63) == 0) r4[t >> 6] = m;
    __syncthreads();
    m = fmaxf(fmaxf(r4[0], r4[1]), fmaxf(r4[2], r4[3]));
    float e[4];
    float s = 0.f;
#pragma unroll
    for (int i = 0; i < 4; i++) {
        e[i] = expf(v[i] - m);
        s += e[i];
    }
#pragma unroll
    for (int off = 1; off < 64; off <<= 1) s += __shfl_xor(s, off);
    if ((t & 63) == 0) r4b[t >> 6] = s;
    __syncthreads();
    s = r4b[0] + r4b[1] + r4b[2] + r4b[3];
    const float inv = 1.f / s;
#pragma unroll
    for (int i = 0; i < 4; i++) a1[(t + i * 256) * BB + b] = e[i] * inv;
}

// ---------------------------------------------------------------------------
// c[b][h] += sum_{p in seg} a1[p][b] * hp[p][b][h].  grid (HH/256, BB, 8)
// ---------------------------------------------------------------------------
__global__ __launch_bounds__(256) void weighted_pool_p(
    const float* __restrict__ hp, const float* __restrict__ a1,
    float* __restrict__ c) {
    const int b = blockIdx.y;
    const int h = blockIdx.x * 256 + threadIdx.x;
    const int ps = blockIdx.z;
    __shared__ float aw[128];
    if (threadIdx.x < 128) aw[threadIdx.x] = a1[(ps * 128 + threadIdx.x) * BB + b];
    __syncthreads();
    float acc = 0.f;
    const long base = ((long)ps * 128 * BB + b) * HH + h;
#pragma unroll 4
    for (int p = 0; p < 128; p++)
        acc += aw[p] * hp[base + (long)p * (BB * HH)];
    atomicAdd(&c[b * HH + h], acc);
}

// ---------------------------------------------------------------------------
// GRU gemms (MFMA split-bf16): gi = c @ W_ih^T, gh = ha0 @ W_hh^T.
// (64 x 3072, K=1024).  grid (3072/64, 2), 256 thr = 4 waves.
// Block: all 64 rows x 64-col tile; wave w owns 16 cols.
// ---------------------------------------------------------------------------
__global__ __launch_bounds__(256) void gru_gemm(
    const float* __restrict__ c, const float* __restrict__ ha0,
    const float* __restrict__ W_ih, const float* __restrict__ W_hh,
    float* __restrict__ gi, float* __restrict__ gh) {
    const float* X = blockIdx.y ? ha0 : c;
    const float* W = blockIdx.y ? W_hh : W_ih;
    float* out = blockIdx.y ? gh : gi;
    const int n0 = blockIdx.x * 64;

    __shared__ unsigned short Ah[64 * LDA], Al[64 * LDA];
    __shared__ unsigned short Bh[64 * LDA], Bl[64 * LDA];

    const int t = threadIdx.x;
    const int w = t >> 6;
    const int l = t & 63;
    const int lr = l & 15;
    const int lg = l >> 4;

    f32x4 acc[4];
#pragma unroll
    for (int mt = 0; mt < 4; mt++) acc[mt] = (f32x4){0.f, 0.f, 0.f, 0.f};

    for (int k0 = 0; k0 < 1024; k0 += 32) {
        __syncthreads();
#pragma unroll
        for (int i = 0; i < 2; i++) {
            const int s = t + i * 256;           // 0..511
            const int row = s >> 3, kq = s & 7;
            const float4 x = *reinterpret_cast<const float4*>(
                X + (size_t)row * 1024 + k0 + kq * 4);
            split_store(Ah, Al, row * LDA + kq * 4, x);
            const float4 wv = *reinterpret_cast<const float4*>(
                W + (size_t)(n0 + row) * 1024 + k0 + kq * 4);
            split_store(Bh, Bl, row * LDA + kq * 4, wv);
        }
        __syncthreads();

        const int br = (w * 16 + lr) * LDA + lg * 8;
        const ushort8 bh = *reinterpret_cast<const ushort8*>(&Bh[br]);
        const ushort8 bl = *reinterpret_cast<const ushort8*>(&Bl[br]);
#pragma unroll
        for (int mt = 0; mt < 4; mt++) {
            const int ar = (mt * 16 + lr) * LDA + lg * 8;
            const ushort8 ah = *reinterpret_cast<const ushort8*>(&Ah[ar]);
            const ushort8 al = *reinterpret_cast<const ushort8*>(&Al[ar]);
            acc[mt] = mfma16(ah, bh, acc[mt]);
            acc[mt] = mfma16(ah, bl, acc[mt]);
            acc[mt] = mfma16(al, bh, acc[mt]);
        }
    }

#pragma unroll
    for (int mt = 0; mt < 4; mt++)
#pragma unroll
        for (int r = 0; r < 4; r++) {
            const int row = mt * 16 + lg * 4 + r;
            const int n = n0 + w * 16 + lr;
            out[(size_t)row * H3 + n] = acc[mt][r];
        }
}

// ---------------------------------------------------------------------------
// GRU gates: torch GRUCell order [r, z, n], no bias.  grid (HH/256, BB)
// ---------------------------------------------------------------------------
__global__ __launch_bounds__(256) void gru_gate(const float* __restrict__ gi,
                                                const float* __restrict__ gh,
                                                const float* __restrict__ ha0,
                                                float* __restrict__ ha1) {
    const int b = blockIdx.y;
    const int hn = blockIdx.x * 256 + threadIdx.x;
    const long o = (long)b * H3 + hn;
    const float r = 1.f / (1.f + expf(-(gi[o] + gh[o])));
    const float z = 1.f / (1.f + expf(-(gi[o + 1024] + gh[o + 1024])));
    const float n = tanhf(gi[o + 2048] + r * gh[o + 2048]);
    ha1[b * HH + hn] = (1.f - z) * n + z * ha0[b * HH + hn];
}

// ---------------------------------------------------------------------------
// end logits: s2[p][b] = sum_a tanh(Wh[r][a] + haW1[b][a]) * vw[a]
// ---------------------------------------------------------------------------
__global__ __launch_bounds__(256) void end_logits_k(
    const float* __restrict__ wh, const float* __restrict__ haW1,
    const float* __restrict__ vw, float* __restrict__ out) {
    const int row0 = blockIdx.x * 64;
    const int t = threadIdx.x;
    const int l = t & 15;
    const int rbase = (t >> 4) * 4;
#pragma unroll
    for (int i = 0; i < 4; i++) {
        const int r = row0 + rbase + i;
        const int b = r & 63;
        float partial = 0.f;
#pragma unroll
        for (int j = 0; j < 5; j++) {
            const int col = l + 16 * j;
            if (col < AA)
                partial +=
                    vw[col] * tanhf(wh[(size_t)r * APAD + col] + haW1[b * APAD + col]);
        }
        partial += __shfl_xor(partial, 1);
        partial += __shfl_xor(partial, 2);
        partial += __shfl_xor(partial, 4);
        partial += __shfl_xor(partial, 8);
        if (l == 0) {
            const int p = r >> 6;
            out[(size_t)BB * PP + b * PP + p] = partial;
        }
    }
}

extern "C" void kernel_launch(void* const* d_in, const int* in_sizes, int n_in,
                              void* d_out, int out_size, void* d_ws,
                              size_t ws_size, hipStream_t stream) {
    const float* hp   = (const float*)d_in[0];  // (P,B,HP)
    const float* u    = (const float*)d_in[1];  // (Q,B,HQ)
    const float* Whp  = (const float*)d_in[2];  // (A,HP)
    const float* Wha  = (const float*)d_in[3];  // (A,HQ)
    const float* v_w  = (const float*)d_in[4];  // (1,A)
    const float* Wuq  = (const float*)d_in[5];  // (A,HQ)
    const float* v1w  = (const float*)d_in[6];  // (1,A)
    const float* v1b  = (const float*)d_in[7];  // (1,)
    const float* W_ih = (const float*)d_in[8];  // (3H,HP)
    const float* W_hh = (const float*)d_in[9];  // (3H,HQ)
    float* out = (float*)d_out;
    float* ws = (float*)d_ws;

    // 1. s_q = tanh(U @ Wuq^T) @ v1 + b1    (M = Q*B = 8192)
    hipLaunchKernelGGL((gemm_attn<false, false, true>), dim3(QQ * BB / 128),
                       dim3(256), 0, stream, u, Wuq, nullptr, v1w, v1b, nullptr,
                       ws + OFF_SQ);
    // 2. softmax over q
    hipLaunchKernelGGL(softmax_q, dim3(BB), dim3(128), 0, stream, ws + OFF_SQ,
                       ws + OFF_AQ);
    // 3. ha0 = sum_q a_q * u
    hipLaunchKernelGGL(pool_q, dim3(HH / 256, BB), dim3(256), 0, stream, u,
                       ws + OFF_AQ, ws + OFF_HA0);
    // 4. haW0 = ha0 @ Wha^T
    hipLaunchKernelGGL(vecmat, dim3(AA, BB), dim3(64), 0, stream, ws + OFF_HA0,
                       Wha, ws + OFF_HAW0);
    // 5. Wh GEMM + s1 epilogue (M = P*B = 65536), stores raw Wh
    hipLaunchKernelGGL((gemm_attn<true, true, false>), dim3(PP * BB / 128),
                       dim3(256), 0, stream, hp, Whp, ws + OFF_HAW0, v_w,
                       nullptr, ws + OFF_WH, ws + OFF_S1);
    // 6. softmax over p + start logits
    hipLaunchKernelGGL(softmax_p, dim3(BB), dim3(256), 0, stream, ws + OFF_S1,
                       ws + OFF_A1, out);
    // 7. c = sum_p a1 * h_passage  (zero + atomic partial sums)
    hipMemsetAsync(ws + OFF_C, 0, (size_t)BB * HH * sizeof(float), stream);
    hipLaunchKernelGGL(weighted_pool_p, dim3(HH / 256, BB, 8), dim3(256), 0,
                       stream, hp, ws + OFF_A1, ws + OFF_C);
    // 8. GRU gemms + gates
    hipLaunchKernelGGL(gru_gemm, dim3(H3 / 64, 2), dim3(256), 0, stream,
                       ws + OFF_C, ws + OFF_HA0, W_ih, W_hh, ws + OFF_GI,
                       ws + OFF_GH);
    hipLaunchKernelGGL(gru_gate, dim3(HH / 256, BB), dim3(256), 0, stream,
                       ws + OFF_GI, ws + OFF_GH, ws + OFF_HA0, ws + OFF_HA1);
    // 9. haW1 = ha1 @ Wha^T
    hipLaunchKernelGGL(vecmat, dim3(AA, BB), dim3(64), 0, stream, ws + OFF_HA1,
                       Wha, ws + OFF_HAW1);
    // 10. end logits from stored Wh
    hipLaunchKernelGGL(end_logits_k, dim3(PP * BB / 64), dim3(256), 0, stream,
                       ws + OFF_WH, ws + OFF_HAW1, v_w, out);
    (void)in_sizes; (void)n_in; (void)out_size; (void)ws_size;
}

// Round 5
// 624.221 us; speedup vs baseline: 1.2905x; 1.1512x over previous
//
#include <hip/hip_runtime.h>
#include <math.h>

// Problem dims
#define PP 1024
#define QQ 128
#define BB 64
#define HH 1024   // HP == HQ
#define AA 75
#define APAD 80
#define H3 3072
#define BM 128
#define BK 32
#define NTILE 32  // 1024/BK
#define LDA 40    // (gru_gemm legacy layout)

// ws offsets (in floats)
#define OFF_SQ    0L          // Q*B = 8192
#define OFF_AQ    8192L       // 8192
#define OFF_HA0   16384L      // 64*1024
#define OFF_HAW0  81920L      // 64*80
#define OFF_WH    87040L      // 65536*80
#define OFF_S1    5329920L    // 65536
#define OFF_A1    5395456L    // 65536
#define OFF_C     5460992L    // 65536
#define OFF_GI    5526528L    // 64*3072   (aliased: Whp-split lives here until step 8)
#define OFF_GH    5723136L    // 64*3072   (aliased: Wuq-split lives here until step 8)
#define OFF_HA1   5919744L    // 64*1024
#define OFF_HAW1  5985280L    // 64*80

typedef __attribute__((ext_vector_type(8))) __bf16 bf16x8;
typedef __attribute__((ext_vector_type(8))) unsigned short ushort8;
typedef __attribute__((ext_vector_type(4))) float f32x4;

__device__ __forceinline__ unsigned short f2bf(float x) {
    unsigned int u = __builtin_bit_cast(unsigned int, x);
    u += 0x7FFFu + ((u >> 16) & 1u);   // RNE
    return (unsigned short)(u >> 16);
}
__device__ __forceinline__ float bf2f(unsigned short h) {
    unsigned int u = ((unsigned int)h) << 16;
    return __builtin_bit_cast(float, u);
}
__device__ __forceinline__ f32x4 mfma16(ushort8 a, ushort8 b, f32x4 c) {
    return __builtin_amdgcn_mfma_f32_16x16x32_bf16(
        __builtin_bit_cast(bf16x8, a), __builtin_bit_cast(bf16x8, b), c, 0, 0, 0);
}
// fp32 -> (bf16 hi, bf16 lo) with lo = x - float(hi); compiler packs cvt pairs
__device__ __forceinline__ void cvt_hilo4(const float4 x, ushort4& h, ushort4& lo) {
    __bf16 a = (__bf16)x.x, b = (__bf16)x.y, c = (__bf16)x.z, d = (__bf16)x.w;
    h.x = __builtin_bit_cast(unsigned short, a);
    h.y = __builtin_bit_cast(unsigned short, b);
    h.z = __builtin_bit_cast(unsigned short, c);
    h.w = __builtin_bit_cast(unsigned short, d);
    lo.x = __builtin_bit_cast(unsigned short, (__bf16)(x.x - (float)a));
    lo.y = __builtin_bit_cast(unsigned short, (__bf16)(x.y - (float)b));
    lo.z = __builtin_bit_cast(unsigned short, (__bf16)(x.z - (float)c));
    lo.w = __builtin_bit_cast(unsigned short, (__bf16)(x.w - (float)d));
}
__device__ __forceinline__ void gl2lds16(const void* g, void* s) {
    __builtin_amdgcn_global_load_lds(
        (const __attribute__((address_space(1))) unsigned int*)g,
        (__attribute__((address_space(3))) unsigned int*)s, 16, 0, 0);
}
__device__ __forceinline__ void split_store(unsigned short* hi, unsigned short* lo,
                                            int idx, float4 x) {
    ushort4 h, l;
    cvt_hilo4(x, h, l);
    *reinterpret_cast<ushort4*>(hi + idx) = h;
    *reinterpret_cast<ushort4*>(lo + idx) = l;
}

// ---------------------------------------------------------------------------
// Pre-split a (75,1024) fp32 weight into bf16 hi/lo, tiled to match the
// LDS-linear layout used by global_load_lds in gemm_attn:
//   dst ushort layout: [tile(32)][hl(2)][kg(4)][a(80)][8]   (a>=75 zeros)
// ---------------------------------------------------------------------------
__global__ __launch_bounds__(256) void split_w(const float* __restrict__ Wsrc,
                                               unsigned short* __restrict__ dst) {
    const int n = blockIdx.x * 256 + threadIdx.x;  // 0 .. 20480-1
    const int a = n % 80;
    const int kg = (n / 80) & 3;
    const int hl = (n / 320) & 1;
    const int tile = n / 640;
    const int k = tile * 32 + kg * 8;
    float4 x0 = make_float4(0.f, 0.f, 0.f, 0.f), x1 = x0;
    if (a < AA) {
        x0 = *reinterpret_cast<const float4*>(Wsrc + (size_t)a * 1024 + k);
        x1 = *reinterpret_cast<const float4*>(Wsrc + (size_t)a * 1024 + k + 4);
    }
    ushort4 h0, l0, h1, l1;
    cvt_hilo4(x0, h0, l0);
    cvt_hilo4(x1, h1, l1);
    ushort8 o;
    if (hl == 0) { o[0]=h0.x; o[1]=h0.y; o[2]=h0.z; o[3]=h0.w; o[4]=h1.x; o[5]=h1.y; o[6]=h1.z; o[7]=h1.w; }
    else         { o[0]=l0.x; o[1]=l0.y; o[2]=l0.z; o[3]=l0.w; o[4]=l1.x; o[5]=l1.y; o[6]=l1.z; o[7]=l1.w; }
    *reinterpret_cast<ushort8*>(dst + (size_t)n * 8) = o;
}

// ---------------------------------------------------------------------------
// Pipelined MFMA GEMM (M x 1024) @ (75 x 1024)^T, split-bf16 (3 mfma/tile).
// All staging via global_load_lds; one raw s_barrier + counted vmcnt(7) per
// K-tile (prefetch for t+1 stays in flight across the barrier).
//   X: fp32 -> LDS (DMA, col-XOR-swizzled src) -> regs -> bf16 hi/lo LDS
//      (wave-local rows: no barrier, single buffer)
//   W: pre-split bf16 hi/lo (split_w layout) -> LDS (DMA, triple-buffered)
// Epilogue: s[r] = sum_a tanh(raw + haW[b][a]) * vw[a] (+bias), b = r & 63.
// ---------------------------------------------------------------------------
template <bool ADD_HAW, bool STORE_RAW, bool ADD_BIAS>
__global__ __launch_bounds__(256) void gemm_attn(
    const float* __restrict__ X,          // (M, 1024)
    const unsigned short* __restrict__ Wsp, // split_w output
    const float* __restrict__ haW,        // (64, 80) padded, or nullptr
    const float* __restrict__ vw,         // (75)
    const float* __restrict__ bias,       // (1) or nullptr
    float* __restrict__ raw_out,          // (M, 80) or nullptr
    float* __restrict__ s_out)            // (M)
{
    __shared__ __align__(16) float X32[2][BM][BK];            // 32 KB, swizzled cols
    __shared__ __align__(16) unsigned short Xbf[2][4][BM][8]; // 16 KB [hl][kg][row][e]
    __shared__ __align__(16) unsigned short Bsh[3][5120];     // 30 KB [hl][kg][a][e]

    const int t = threadIdx.x;
    const int w = t >> 6;          // wave
    const int l = t & 63;
    const int lr = l & 15;         // frag row/col
    const int lg = l >> 4;         // frag k-group
    const int l3 = l >> 3;         // 0..7
    const int l7 = l & 7;          // 0..7
    const int row0 = blockIdx.x * BM;

    float vwv[5];
#pragma unroll
    for (int nt = 0; nt < 5; nt++) {
        const int col = lr + 16 * nt;
        vwv[nt] = (col < AA) ? vw[col] : 0.f;
    }
    // drain prologue loads so the loop's vmcnt counting is exact
    asm volatile("s_waitcnt vmcnt(0)" ::: "memory");

    f32x4 acc[2][5];
#pragma unroll
    for (int mt = 0; mt < 2; mt++)
#pragma unroll
        for (int nt = 0; nt < 5; nt++) acc[mt][nt] = (f32x4){0.f, 0.f, 0.f, 0.f};

    const int swz = (l7 ^ l3);     // XOR col-swizzle (conflict-free fp32 reads)

#define ISSUE_X(tile, buf)                                                      \
    {                                                                           \
        _Pragma("unroll")                                                       \
        for (int c = 0; c < 4; c++) {                                           \
            const int r = w * 32 + c * 8 + l3;                                  \
            const float* src = X + (size_t)(row0 + r) * 1024 + (tile) * BK + swz * 4; \
            gl2lds16(src, &X32[buf][w * 32 + c * 8][0]);                        \
        }                                                                       \
    }
#define ISSUE_B(tile, bufb)                                                     \
    {                                                                           \
        _Pragma("unroll")                                                       \
        for (int j = 0; j < 3; j++) {                                           \
            int cc = w * 3 + j;                                                 \
            if (cc >= 10) cc -= 10; /* dup chunks: idempotent */                \
            const unsigned short* src = Wsp + (size_t)(tile) * 5120 + cc * 512 + l * 8; \
            gl2lds16(src, &Bsh[bufb][cc * 512]);                                \
        }                                                                       \
    }

    // prologue: tile 0 in flight
    ISSUE_X(0, 0);
    ISSUE_B(0, 0);

    for (int tt = 0; tt < NTILE; ++tt) {
        const int cur = tt & 1;
        const int bufB = tt % 3;
        if (tt + 1 < NTILE) {
            ISSUE_X(tt + 1, cur ^ 1);
            ISSUE_B(tt + 1, (tt + 1) % 3);
            asm volatile("s_waitcnt vmcnt(7)" ::: "memory");  // tile tt arrived
        } else {
            asm volatile("s_waitcnt vmcnt(0)" ::: "memory");
        }
        __builtin_amdgcn_sched_barrier(0);

        // convert this wave's 32 rows: fp32 LDS -> regs -> bf16 hi/lo LDS
#pragma unroll
        for (int i = 0; i < 4; i++) {
            const int r = w * 32 + i * 8 + l3;
            const float4 x = *reinterpret_cast<const float4*>(&X32[cur][r][swz * 4]);
            ushort4 h, lo;
            cvt_hilo4(x, h, lo);
            const int kg = l7 >> 1, hf = (l7 & 1) * 4;
            *reinterpret_cast<ushort4*>(&Xbf[0][kg][r][hf]) = h;
            *reinterpret_cast<ushort4*>(&Xbf[1][kg][r][hf]) = lo;
        }

        asm volatile("s_barrier" ::: "memory");  // B-tile visibility (no vmcnt drain)

        ushort8 ah0h, ah0l, ah1h, ah1l;
        ah0h = *reinterpret_cast<const ushort8*>(&Xbf[0][lg][w * 32 + 0 + lr][0]);
        ah0l = *reinterpret_cast<const ushort8*>(&Xbf[1][lg][w * 32 + 0 + lr][0]);
        ah1h = *reinterpret_cast<const ushort8*>(&Xbf[0][lg][w * 32 + 16 + lr][0]);
        ah1l = *reinterpret_cast<const ushort8*>(&Xbf[1][lg][w * 32 + 16 + lr][0]);
#pragma unroll
        for (int nt = 0; nt < 5; nt++) {
            const int aoff = lg * 640 + (nt * 16 + lr) * 8;
            const ushort8 bh = *reinterpret_cast<const ushort8*>(&Bsh[bufB][aoff]);
            const ushort8 bl = *reinterpret_cast<const ushort8*>(&Bsh[bufB][2560 + aoff]);
            acc[0][nt] = mfma16(ah0h, bh, acc[0][nt]);
            acc[0][nt] = mfma16(ah0h, bl, acc[0][nt]);
            acc[0][nt] = mfma16(ah0l, bh, acc[0][nt]);
            acc[1][nt] = mfma16(ah1h, bh, acc[1][nt]);
            acc[1][nt] = mfma16(ah1h, bl, acc[1][nt]);
            acc[1][nt] = mfma16(ah1l, bh, acc[1][nt]);
        }
    }
#undef ISSUE_X
#undef ISSUE_B

    // Epilogue: D mapping col = lane&15, row = (lane>>4)*4 + reg
#pragma unroll
    for (int mt = 0; mt < 2; mt++) {
#pragma unroll
        for (int r = 0; r < 4; r++) {
            const int row_local = w * 32 + mt * 16 + lg * 4 + r;
            const int rg = row0 + row_local;
            const int b = rg & 63;
            float partial = 0.f;
#pragma unroll
            for (int nt = 0; nt < 5; nt++) {
                const int col = lr + 16 * nt;
                const float v = acc[mt][nt][r];
                if (STORE_RAW) raw_out[(size_t)rg * APAD + col] = v;
                if (col < AA) {
                    float hw = 0.f;
                    if (ADD_HAW) hw = haW[b * APAD + col];
                    partial += vwv[nt] * tanhf(v + hw);
                }
            }
            partial += __shfl_xor(partial, 1);
            partial += __shfl_xor(partial, 2);
            partial += __shfl_xor(partial, 4);
            partial += __shfl_xor(partial, 8);
            if (lr == 0) {
                if (ADD_BIAS) partial += bias[0];
                s_out[rg] = partial;
            }
        }
    }
}

// ---------------------------------------------------------------------------
// Softmax over q (axis 0) of s_q (Q=128, B=64): one block per b, 128 threads
// ---------------------------------------------------------------------------
__global__ __launch_bounds__(128) void softmax_q(const float* __restrict__ sq,
                                                 float* __restrict__ aq) {
    const int b = blockIdx.x;
    const int q = threadIdx.x;
    __shared__ float red[2], red2[2];
    float v = sq[q * BB + b];
    float m = v;
#pragma unroll
    for (int off = 1; off < 64; off <<= 1) m = fmaxf(m, __shfl_xor(m, off));
    if ((q & 63) == 0) red[q >> 6] = m;
    __syncthreads();
    m = fmaxf(red[0], red[1]);
    float e = expf(v - m);
    float s = e;
#pragma unroll
    for (int off = 1; off < 64; off <<= 1) s += __shfl_xor(s, off);
    if ((q & 63) == 0) red2[q >> 6] = s;
    __syncthreads();
    s = red2[0] + red2[1];
    aq[q * BB + b] = e / s;
}

// ---------------------------------------------------------------------------
// ha0[b][h] = sum_q aq[q][b] * u[q][b][h].  grid (HH/256, BB), 256 thr
// ---------------------------------------------------------------------------
__global__ __launch_bounds__(256) void pool_q(const float* __restrict__ u,
                                              const float* __restrict__ aq,
                                              float* __restrict__ ha0) {
    const int b = blockIdx.y;
    const int h = blockIdx.x * 256 + threadIdx.x;
    __shared__ float aw[QQ];
    if (threadIdx.x < QQ) aw[threadIdx.x] = aq[threadIdx.x * BB + b];
    __syncthreads();
    float acc = 0.f;
#pragma unroll 4
    for (int q = 0; q < QQ; q++)
        acc += aw[q] * u[(q * BB + b) * HH + h];
    ha0[b * HH + h] = acc;
}

// ---------------------------------------------------------------------------
// out[b][a] = sum_h x[b][h] * W[a][h].  grid (AA, BB), 64 threads
// ---------------------------------------------------------------------------
__global__ __launch_bounds__(64) void vecmat(const float* __restrict__ x,
                                             const float* __restrict__ W,
                                             float* __restrict__ out) {
    const int a = blockIdx.x, b = blockIdx.y, l = threadIdx.x;
    float s = 0.f;
#pragma unroll 4
    for (int k = l; k < HH; k += 64) s += x[b * HH + k] * W[a * HH + k];
#pragma unroll
    for (int off = 1; off < 64; off <<= 1) s += __shfl_xor(s, off);
    if (l == 0) out[b * APAD + a] = s;
}

// ---------------------------------------------------------------------------
// Softmax over p of s1 (P=1024, B=64) + write start logits.
// ---------------------------------------------------------------------------
__global__ __launch_bounds__(256) void softmax_p(const float* __restrict__ s1,
                                                 float* __restrict__ a1,
                                                 float* __restrict__ outStart) {
    const int b = blockIdx.x;
    const int t = threadIdx.x;
    __shared__ float r4[4], r4b[4];
    float v[4];
    float m = -1e30f;
#pragma unroll
    for (int i = 0; i < 4; i++) {
        const int p = t + i * 256;
        v[i] = s1[p * BB + b];
        outStart[b * PP + p] = v[i];
        m = fmaxf(m, v[i]);
    }
#pragma unroll
    for (int off = 1; off < 64; off <<= 1) m = fmaxf(m, __shfl_xor(m, off));
    if ((t & 63) == 0) r4[t >> 6] = m;
    __syncthreads();
    m = fmaxf(fmaxf(r4[0], r4[1]), fmaxf(r4[2], r4[3]));
    float e[4];
    float s = 0.f;
#pragma unroll
    for (int i = 0; i < 4; i++) {
        e[i] = expf(v[i] - m);
        s += e[i];
    }
#pragma unroll
    for (int off = 1; off < 64; off <<= 1) s += __shfl_xor(s, off);
    if ((t & 63) == 0) r4b[t >> 6] = s;
    __syncthreads();
    s = r4b[0] + r4b[1] + r4b[2] + r4b[3];
    const float inv = 1.f / s;
#pragma unroll
    for (int i = 0; i < 4; i++) a1[(t + i * 256) * BB + b] = e[i] * inv;
}

// ---------------------------------------------------------------------------
// c[b][h] += sum_{p in seg} a1[p][b] * hp[p][b][h].  grid (HH/256, BB, 8)
// ---------------------------------------------------------------------------
__global__ __launch_bounds__(256) void weighted_pool_p(
    const float* __restrict__ hp, const float* __restrict__ a1,
    float* __restrict__ c) {
    const int b = blockIdx.y;
    const int h = blockIdx.x * 256 + threadIdx.x;
    const int ps = blockIdx.z;
    __shared__ float aw[128];
    if (threadIdx.x < 128) aw[threadIdx.x] = a1[(ps * 128 + threadIdx.x) * BB + b];
    __syncthreads();
    float acc = 0.f;
    const long base = ((long)ps * 128 * BB + b) * HH + h;
#pragma unroll 4
    for (int p = 0; p < 128; p++)
        acc += aw[p] * hp[base + (long)p * (BB * HH)];
    atomicAdd(&c[b * HH + h], acc);
}

// ---------------------------------------------------------------------------
// GRU gemms (MFMA split-bf16): gi = c @ W_ih^T, gh = ha0 @ W_hh^T.
// (64 x 3072, K=1024).  grid (3072/64, 2), 256 thr = 4 waves.
// ---------------------------------------------------------------------------
__global__ __launch_bounds__(256) void gru_gemm(
    const float* __restrict__ c, const float* __restrict__ ha0,
    const float* __restrict__ W_ih, const float* __restrict__ W_hh,
    float* __restrict__ gi, float* __restrict__ gh) {
    const float* X = blockIdx.y ? ha0 : c;
    const float* W = blockIdx.y ? W_hh : W_ih;
    float* out = blockIdx.y ? gh : gi;
    const int n0 = blockIdx.x * 64;

    __shared__ unsigned short Ah[64 * LDA], Al[64 * LDA];
    __shared__ unsigned short Bh[64 * LDA], Bl[64 * LDA];

    const int t = threadIdx.x;
    const int w = t >> 6;
    const int l = t & 63;
    const int lr = l & 15;
    const int lg = l >> 4;

    f32x4 acc[4];
#pragma unroll
    for (int mt = 0; mt < 4; mt++) acc[mt] = (f32x4){0.f, 0.f, 0.f, 0.f};

    for (int k0 = 0; k0 < 1024; k0 += 32) {
        __syncthreads();
#pragma unroll
        for (int i = 0; i < 2; i++) {
            const int s = t + i * 256;           // 0..511
            const int row = s >> 3, kq = s & 7;
            const float4 x = *reinterpret_cast<const float4*>(
                X + (size_t)row * 1024 + k0 + kq * 4);
            split_store(Ah, Al, row * LDA + kq * 4, x);
            const float4 wv = *reinterpret_cast<const float4*>(
                W + (size_t)(n0 + row) * 1024 + k0 + kq * 4);
            split_store(Bh, Bl, row * LDA + kq * 4, wv);
        }
        __syncthreads();

        const int br = (w * 16 + lr) * LDA + lg * 8;
        const ushort8 bh = *reinterpret_cast<const ushort8*>(&Bh[br]);
        const ushort8 bl = *reinterpret_cast<const ushort8*>(&Bl[br]);
#pragma unroll
        for (int mt = 0; mt < 4; mt++) {
            const int ar = (mt * 16 + lr) * LDA + lg * 8;
            const ushort8 ah = *reinterpret_cast<const ushort8*>(&Ah[ar]);
            const ushort8 al = *reinterpret_cast<const ushort8*>(&Al[ar]);
            acc[mt] = mfma16(ah, bh, acc[mt]);
            acc[mt] = mfma16(ah, bl, acc[mt]);
            acc[mt] = mfma16(al, bh, acc[mt]);
        }
    }

#pragma unroll
    for (int mt = 0; mt < 4; mt++)
#pragma unroll
        for (int r = 0; r < 4; r++) {
            const int row = mt * 16 + lg * 4 + r;
            const int n = n0 + w * 16 + lr;
            out[(size_t)row * H3 + n] = acc[mt][r];
        }
}

// ---------------------------------------------------------------------------
// GRU gates: torch GRUCell order [r, z, n], no bias.  grid (HH/256, BB)
// ---------------------------------------------------------------------------
__global__ __launch_bounds__(256) void gru_gate(const float* __restrict__ gi,
                                                const float* __restrict__ gh,
                                                const float* __restrict__ ha0,
                                                float* __restrict__ ha1) {
    const int b = blockIdx.y;
    const int hn = blockIdx.x * 256 + threadIdx.x;
    const long o = (long)b * H3 + hn;
    const float r = 1.f / (1.f + expf(-(gi[o] + gh[o])));
    const float z = 1.f / (1.f + expf(-(gi[o + 1024] + gh[o + 1024])));
    const float n = tanhf(gi[o + 2048] + r * gh[o + 2048]);
    ha1[b * HH + hn] = (1.f - z) * n + z * ha0[b * HH + hn];
}

// ---------------------------------------------------------------------------
// end logits: s2[p][b] = sum_a tanh(Wh[r][a] + haW1[b][a]) * vw[a]
// ---------------------------------------------------------------------------
__global__ __launch_bounds__(256) void end_logits_k(
    const float* __restrict__ wh, const float* __restrict__ haW1,
    const float* __restrict__ vw, float* __restrict__ out) {
    const int row0 = blockIdx.x * 64;
    const int t = threadIdx.x;
    const int l = t & 15;
    const int rbase = (t >> 4) * 4;
#pragma unroll
    for (int i = 0; i < 4; i++) {
        const int r = row0 + rbase + i;
        const int b = r & 63;
        float partial = 0.f;
#pragma unroll
        for (int j = 0; j < 5; j++) {
            const int col = l + 16 * j;
            if (col < AA)
                partial +=
                    vw[col] * tanhf(wh[(size_t)r * APAD + col] + haW1[b * APAD + col]);
        }
        partial += __shfl_xor(partial, 1);
        partial += __shfl_xor(partial, 2);
        partial += __shfl_xor(partial, 4);
        partial += __shfl_xor(partial, 8);
        if (l == 0) {
            const int p = r >> 6;
            out[(size_t)BB * PP + b * PP + p] = partial;
        }
    }
}

extern "C" void kernel_launch(void* const* d_in, const int* in_sizes, int n_in,
                              void* d_out, int out_size, void* d_ws,
                              size_t ws_size, hipStream_t stream) {
    const float* hp   = (const float*)d_in[0];  // (P,B,HP)
    const float* u    = (const float*)d_in[1];  // (Q,B,HQ)
    const float* Whp  = (const float*)d_in[2];  // (A,HP)
    const float* Wha  = (const float*)d_in[3];  // (A,HQ)
    const float* v_w  = (const float*)d_in[4];  // (1,A)
    const float* Wuq  = (const float*)d_in[5];  // (A,HQ)
    const float* v1w  = (const float*)d_in[6];  // (1,A)
    const float* v1b  = (const float*)d_in[7];  // (1,)
    const float* W_ih = (const float*)d_in[8];  // (3H,HP)
    const float* W_hh = (const float*)d_in[9];  // (3H,HQ)
    float* out = (float*)d_out;
    float* ws = (float*)d_ws;
    // Pre-split weight buffers alias gi/gh scratch (dead until step 8)
    unsigned short* wsp_hp = (unsigned short*)(ws + OFF_GI);
    unsigned short* wsp_uq = (unsigned short*)(ws + OFF_GH);

    // 0. pre-split Whp / Wuq into bf16 hi/lo (LDS-linear tiled layout)
    hipLaunchKernelGGL(split_w, dim3(80), dim3(256), 0, stream, Whp, wsp_hp);
    hipLaunchKernelGGL(split_w, dim3(80), dim3(256), 0, stream, Wuq, wsp_uq);
    // 1. s_q = tanh(U @ Wuq^T) @ v1 + b1    (M = Q*B = 8192)
    hipLaunchKernelGGL((gemm_attn<false, false, true>), dim3(QQ * BB / BM),
                       dim3(256), 0, stream, u, wsp_uq, nullptr, v1w, v1b,
                       nullptr, ws + OFF_SQ);
    // 2. softmax over q
    hipLaunchKernelGGL(softmax_q, dim3(BB), dim3(128), 0, stream, ws + OFF_SQ,
                       ws + OFF_AQ);
    // 3. ha0 = sum_q a_q * u
    hipLaunchKernelGGL(pool_q, dim3(HH / 256, BB), dim3(256), 0, stream, u,
                       ws + OFF_AQ, ws + OFF_HA0);
    // 4. haW0 = ha0 @ Wha^T
    hipLaunchKernelGGL(vecmat, dim3(AA, BB), dim3(64), 0, stream, ws + OFF_HA0,
                       Wha, ws + OFF_HAW0);
    // 5. Wh GEMM + s1 epilogue (M = P*B = 65536), stores raw Wh
    hipLaunchKernelGGL((gemm_attn<true, true, false>), dim3(PP * BB / BM),
                       dim3(256), 0, stream, hp, wsp_hp, ws + OFF_HAW0, v_w,
                       nullptr, ws + OFF_WH, ws + OFF_S1);
    // 6. softmax over p + start logits
    hipLaunchKernelGGL(softmax_p, dim3(BB), dim3(256), 0, stream, ws + OFF_S1,
                       ws + OFF_A1, out);
    // 7. c = sum_p a1 * h_passage  (zero + atomic partial sums)
    hipMemsetAsync(ws + OFF_C, 0, (size_t)BB * HH * sizeof(float), stream);
    hipLaunchKernelGGL(weighted_pool_p, dim3(HH / 256, BB, 8), dim3(256), 0,
                       stream, hp, ws + OFF_A1, ws + OFF_C);
    // 8. GRU gemms + gates (overwrites gi/gh: pre-split weights dead by now)
    hipLaunchKernelGGL(gru_gemm, dim3(H3 / 64, 2), dim3(256), 0, stream,
                       ws + OFF_C, ws + OFF_HA0, W_ih, W_hh, ws + OFF_GI,
                       ws + OFF_GH);
    hipLaunchKernelGGL(gru_gate, dim3(HH / 256, BB), dim3(256), 0, stream,
                       ws + OFF_GI, ws + OFF_GH, ws + OFF_HA0, ws + OFF_HA1);
    // 9. haW1 = ha1 @ Wha^T
    hipLaunchKernelGGL(vecmat, dim3(AA, BB), dim3(64), 0, stream, ws + OFF_HA1,
                       Wha, ws + OFF_HAW1);
    // 10. end logits from stored Wh
    hipLaunchKernelGGL(end_logits_k, dim3(PP * BB / 64), dim3(256), 0, stream,
                       ws + OFF_WH, ws + OFF_HAW1, v_w, out);
    (void)in_sizes; (void)n_in; (void)out_size; (void)ws_size;
}

// Round 6
// 607.505 us; speedup vs baseline: 1.3260x; 1.0275x over previous
//
#include <hip/hip_runtime.h>
#include <math.h>

// Problem dims
#define PP 1024
#define QQ 128
#define BB 64
#define HH 1024   // HP == HQ
#define AA 75
#define APAD 80
#define H3 3072
#define BM 128
#define BK 32
#define NTILE 32  // 1024/BK
#define LDA 40    // (gru_gemm LDS layout)

// ws offsets (in floats)
#define OFF_SQ    0L          // 64*128 (sq transposed [b][q])
#define OFF_AQ    8192L       // (unused)
#define OFF_HA0   16384L      // 64*1024
#define OFF_HAW0  81920L      // 64*80
#define OFF_WH    87040L      // 65536*80
#define OFF_S1    5329920L    // 65536  ([b][p])
#define OFF_A1    5395456L    // 65536  ([b][p])
#define OFF_C     5460992L    // 65536
#define OFF_GI    5526528L    // 64*3072   (aliased: Whp-split until step 8)
#define OFF_GH    5723136L    // 64*3072   (aliased: Wuq-split until step 8)
#define OFF_HA1   5919744L    // (unused)
#define OFF_HAW1  5985280L    // 64*80

typedef __attribute__((ext_vector_type(8))) __bf16 bf16x8;
typedef __attribute__((ext_vector_type(8))) unsigned short ushort8;
typedef __attribute__((ext_vector_type(4))) float f32x4;

__device__ __forceinline__ f32x4 mfma16(ushort8 a, ushort8 b, f32x4 c) {
    return __builtin_amdgcn_mfma_f32_16x16x32_bf16(
        __builtin_bit_cast(bf16x8, a), __builtin_bit_cast(bf16x8, b), c, 0, 0, 0);
}
// fp32 -> (bf16 hi, bf16 lo) with lo = x - float(hi)
__device__ __forceinline__ void cvt_hilo4(const float4 x, ushort4& h, ushort4& lo) {
    __bf16 a = (__bf16)x.x, b = (__bf16)x.y, c = (__bf16)x.z, d = (__bf16)x.w;
    h.x = __builtin_bit_cast(unsigned short, a);
    h.y = __builtin_bit_cast(unsigned short, b);
    h.z = __builtin_bit_cast(unsigned short, c);
    h.w = __builtin_bit_cast(unsigned short, d);
    lo.x = __builtin_bit_cast(unsigned short, (__bf16)(x.x - (float)a));
    lo.y = __builtin_bit_cast(unsigned short, (__bf16)(x.y - (float)b));
    lo.z = __builtin_bit_cast(unsigned short, (__bf16)(x.z - (float)c));
    lo.w = __builtin_bit_cast(unsigned short, (__bf16)(x.w - (float)d));
}
__device__ __forceinline__ void gl2lds16(const void* g, void* s) {
    __builtin_amdgcn_global_load_lds(
        (const __attribute__((address_space(1))) unsigned int*)g,
        (__attribute__((address_space(3))) unsigned int*)s, 16, 0, 0);
}
__device__ __forceinline__ void split_store(unsigned short* hi, unsigned short* lo,
                                            int idx, float4 x) {
    ushort4 h, l;
    cvt_hilo4(x, h, l);
    *reinterpret_cast<ushort4*>(hi + idx) = h;
    *reinterpret_cast<ushort4*>(lo + idx) = l;
}

// ---------------------------------------------------------------------------
// Pre-split a (75,1024) fp32 weight into bf16 hi/lo, tiled to the LDS-linear
// layout consumed via global_load_lds: ushort [tile(32)][hl(2)][kg(4)][a(80)][8]
// ---------------------------------------------------------------------------
__global__ __launch_bounds__(256) void split_w(const float* __restrict__ Wsrc,
                                               unsigned short* __restrict__ dst) {
    const int n = blockIdx.x * 256 + threadIdx.x;  // 0 .. 20480-1
    const int a = n % 80;
    const int kg = (n / 80) & 3;
    const int hl = (n / 320) & 1;
    const int tile = n / 640;
    const int k = tile * 32 + kg * 8;
    float4 x0 = make_float4(0.f, 0.f, 0.f, 0.f), x1 = x0;
    if (a < AA) {
        x0 = *reinterpret_cast<const float4*>(Wsrc + (size_t)a * 1024 + k);
        x1 = *reinterpret_cast<const float4*>(Wsrc + (size_t)a * 1024 + k + 4);
    }
    ushort4 h0, l0, h1, l1;
    cvt_hilo4(x0, h0, l0);
    cvt_hilo4(x1, h1, l1);
    ushort8 o;
    if (hl == 0) { o[0]=h0.x; o[1]=h0.y; o[2]=h0.z; o[3]=h0.w; o[4]=h1.x; o[5]=h1.y; o[6]=h1.z; o[7]=h1.w; }
    else         { o[0]=l0.x; o[1]=l0.y; o[2]=l0.z; o[3]=l0.w; o[4]=l1.x; o[5]=l1.y; o[6]=l1.z; o[7]=l1.w; }
    *reinterpret_cast<ushort8*>(dst + (size_t)n * 8) = o;
}

// ---------------------------------------------------------------------------
// Pipelined MFMA GEMM (M x 1024) @ (75 x 1024)^T, split-bf16 (3 mfma/tile).
//   X: fp32 -> REGISTERS (2-tile-deep prefetch) -> bf16 hi/lo LDS (wave-local)
//   W: pre-split bf16 hi/lo -> LDS via global_load_lds (4 bufs, 2-tile-deep)
// Correctness w/o manual vmcnt: per phase, B-DMA issued BEFORE X-reg loads;
// compiler's reg-dependency wait for X(t) => B(t) retired (in-order vmcnt);
// raw s_barrier then publishes across waves. 4 B-buffers give a full barrier
// between a buffer's last read and its re-fill DMA issue.
// Epilogue: s[r] = sum_a tanh(raw + haW[b][a]) * vw[a] (+bias), b = r & 63;
// s_out written transposed: s_out[(r&63)*sstr + (r>>6)].
// ---------------------------------------------------------------------------
template <bool ADD_HAW, bool STORE_RAW, bool ADD_BIAS>
__global__ __launch_bounds__(256) void gemm_attn(
    const float* __restrict__ X,            // (M, 1024)
    const unsigned short* __restrict__ Wsp, // split_w output
    const float* __restrict__ haW,          // (64, 80) padded, or nullptr
    const float* __restrict__ vw,           // (75)
    const float* __restrict__ bias,         // (1) or nullptr
    float* __restrict__ raw_out,            // (M, 80) or nullptr
    float* __restrict__ s_out,              // (sstr*64) transposed
    const int sstr)                         // M/64
{
    __shared__ __align__(16) unsigned short Xbf[2][4][BM][8]; // 16 KB [hl][kg][row][e]
    __shared__ __align__(16) unsigned short Bsh[4][5120];     // 40 KB [hl][kg][a][e]

    const int t = threadIdx.x;
    const int w = t >> 6, l = t & 63;
    const int lr = l & 15, lg = l >> 4;
    const int l3 = l >> 3, l7 = l & 7;
    const int row0 = blockIdx.x * BM;

    float vwv[5];
#pragma unroll
    for (int nt = 0; nt < 5; nt++) {
        const int col = lr + 16 * nt;
        vwv[nt] = (col < AA) ? vw[col] : 0.f;
    }

    f32x4 acc[2][5];
#pragma unroll
    for (int mt = 0; mt < 2; mt++)
#pragma unroll
        for (int nt = 0; nt < 5; nt++) acc[mt][nt] = (f32x4){0.f, 0.f, 0.f, 0.f};

    const float* xbase = X + (size_t)(row0 + w * 32 + l3) * 1024 + l7 * 4;

#define SB __builtin_amdgcn_sched_barrier(0)
#define BAR asm volatile("s_barrier" ::: "memory")
#define ISSUE_B(tile)                                                           \
    {                                                                           \
        _Pragma("unroll")                                                       \
        for (int j = 0; j < 3; j++) {                                           \
            int cc = w * 3 + j;                                                 \
            if (cc >= 10) cc -= 10; /* dup chunks: identical data, benign */    \
            gl2lds16(Wsp + (size_t)(tile) * 5120 + cc * 512 + l * 8,            \
                     &Bsh[(tile) & 3][cc * 512]);                               \
        }                                                                       \
    }
#define LOADX(tile, v0, v1, v2, v3)                                             \
    {                                                                           \
        const float* p_ = xbase + (tile) * BK;                                  \
        v0 = *reinterpret_cast<const float4*>(p_);                              \
        v1 = *reinterpret_cast<const float4*>(p_ + 8 * 1024);                   \
        v2 = *reinterpret_cast<const float4*>(p_ + 16 * 1024);                  \
        v3 = *reinterpret_cast<const float4*>(p_ + 24 * 1024);                  \
    }
#define CVT1(vv, c)                                                             \
    {                                                                           \
        ushort4 h_, lo_;                                                        \
        cvt_hilo4(vv, h_, lo_);                                                 \
        const int r_ = w * 32 + (c) * 8 + l3;                                   \
        *reinterpret_cast<ushort4*>(&Xbf[0][l7 >> 1][r_][(l7 & 1) * 4]) = h_;   \
        *reinterpret_cast<ushort4*>(&Xbf[1][l7 >> 1][r_][(l7 & 1) * 4]) = lo_;  \
    }
#define MFMA_PHASE(buf)                                                         \
    {                                                                           \
        const unsigned short* Bp = &Bsh[(buf)][0];                              \
        const ushort8 ah0h = *reinterpret_cast<const ushort8*>(&Xbf[0][lg][w * 32 + lr][0]);      \
        const ushort8 ah0l = *reinterpret_cast<const ushort8*>(&Xbf[1][lg][w * 32 + lr][0]);      \
        const ushort8 ah1h = *reinterpret_cast<const ushort8*>(&Xbf[0][lg][w * 32 + 16 + lr][0]); \
        const ushort8 ah1l = *reinterpret_cast<const ushort8*>(&Xbf[1][lg][w * 32 + 16 + lr][0]); \
        _Pragma("unroll")                                                       \
        for (int nt = 0; nt < 5; nt++) {                                        \
            const int aoff = lg * 640 + (nt * 16 + lr) * 8;                     \
            const ushort8 bh = *reinterpret_cast<const ushort8*>(&Bp[aoff]);    \
            const ushort8 bl = *reinterpret_cast<const ushort8*>(&Bp[2560 + aoff]); \
            acc[0][nt] = mfma16(ah0h, bh, acc[0][nt]);                          \
            acc[0][nt] = mfma16(ah0h, bl, acc[0][nt]);                          \
            acc[0][nt] = mfma16(ah0l, bh, acc[0][nt]);                          \
            acc[1][nt] = mfma16(ah1h, bh, acc[1][nt]);                          \
            acc[1][nt] = mfma16(ah1h, bl, acc[1][nt]);                          \
            acc[1][nt] = mfma16(ah1l, bh, acc[1][nt]);                          \
        }                                                                       \
    }

    float4 a0, a1, a2, a3, b0, b1, b2, b3;
    // prologue: tiles 0,1 in flight (B before X each tile)
    ISSUE_B(0); SB;
    LOADX(0, a0, a1, a2, a3); SB;
    ISSUE_B(1); SB;
    LOADX(1, b0, b1, b2, b3); SB;

    for (int tt = 0; tt < NTILE; tt += 2) {
        // even phase (set a)
        CVT1(a0, 0); CVT1(a1, 1); CVT1(a2, 2); CVT1(a3, 3);
        if (tt + 2 < NTILE) { ISSUE_B(tt + 2); SB; LOADX(tt + 2, a0, a1, a2, a3); SB; }
        BAR;
        MFMA_PHASE(tt & 3);
        // odd phase (set b)
        CVT1(b0, 0); CVT1(b1, 1); CVT1(b2, 2); CVT1(b3, 3);
        if (tt + 3 < NTILE) { ISSUE_B(tt + 3); SB; LOADX(tt + 3, b0, b1, b2, b3); SB; }
        BAR;
        MFMA_PHASE((tt + 1) & 3);
    }
#undef SB
#undef BAR
#undef ISSUE_B
#undef LOADX
#undef CVT1
#undef MFMA_PHASE

    // Epilogue: D mapping col = lane&15, row = (lane>>4)*4 + reg
#pragma unroll
    for (int mt = 0; mt < 2; mt++) {
#pragma unroll
        for (int r = 0; r < 4; r++) {
            const int rg = row0 + w * 32 + mt * 16 + lg * 4 + r;
            const int b = rg & 63;
            float partial = 0.f;
#pragma unroll
            for (int nt = 0; nt < 5; nt++) {
                const int col = lr + 16 * nt;
                const float v = acc[mt][nt][r];
                if (STORE_RAW) raw_out[(size_t)rg * APAD + col] = v;
                if (col < AA) {
                    float hw = 0.f;
                    if (ADD_HAW) hw = haW[b * APAD + col];
                    partial += vwv[nt] * tanhf(v + hw);
                }
            }
            partial += __shfl_xor(partial, 1);
            partial += __shfl_xor(partial, 2);
            partial += __shfl_xor(partial, 4);
            partial += __shfl_xor(partial, 8);
            if (lr == 0) {
                if (ADD_BIAS) partial += bias[0];
                s_out[(size_t)b * sstr + (rg >> 6)] = partial;
            }
        }
    }
}

// ---------------------------------------------------------------------------
// Fused initial state: softmax over q of sq[b][q], ha0 = sum_q a_q u[q][b][:],
// haW0[b][a] = ha0 . Wha[a].  grid (BB), 512 threads.
// ---------------------------------------------------------------------------
__global__ __launch_bounds__(512) void init_state(
    const float* __restrict__ u, const float* __restrict__ sq,
    const float* __restrict__ Wha, float* __restrict__ ha0,
    float* __restrict__ haW0) {
    const int b = blockIdx.x;
    const int t = threadIdx.x;
    __shared__ float aw[QQ];
    __shared__ float ha0s[HH];
    if (t < QQ) aw[t] = sq[b * QQ + t];
    __syncthreads();
    if (t < 64) {
        float m = fmaxf(aw[t], aw[t + 64]);
#pragma unroll
        for (int off = 1; off < 64; off <<= 1) m = fmaxf(m, __shfl_xor(m, off));
        const float e0 = expf(aw[t] - m), e1 = expf(aw[t + 64] - m);
        float s = e0 + e1;
#pragma unroll
        for (int off = 1; off < 64; off <<= 1) s += __shfl_xor(s, off);
        const float inv = 1.f / s;
        aw[t] = e0 * inv;
        aw[t + 64] = e1 * inv;
    }
    __syncthreads();
#pragma unroll
    for (int j = 0; j < 2; j++) {
        const int h = t + j * 512;
        float acc = 0.f;
#pragma unroll 4
        for (int q = 0; q < QQ; q++)
            acc += aw[q] * u[(size_t)(q * BB + b) * HH + h];
        ha0s[h] = acc;
        ha0[b * HH + h] = acc;
    }
    __syncthreads();
    const int w8 = t >> 6, l = t & 63;
    for (int a = w8; a < AA; a += 8) {
        float s = 0.f;
#pragma unroll
        for (int j = 0; j < 16; j++)
            s += ha0s[l + 64 * j] * Wha[(size_t)a * HH + l + 64 * j];
#pragma unroll
        for (int off = 1; off < 64; off <<= 1) s += __shfl_xor(s, off);
        if (l == 0) haW0[b * APAD + a] = s;
    }
}

// ---------------------------------------------------------------------------
// Softmax over p of s1[b][p] + write start logits.  grid (BB), 256 thr.
// ---------------------------------------------------------------------------
__global__ __launch_bounds__(256) void softmax_p(const float* __restrict__ s1,
                                                 float* __restrict__ a1,
                                                 float* __restrict__ outStart) {
    const int b = blockIdx.x;
    const int t = threadIdx.x;
    __shared__ float r4[4], r4b[4];
    float v[4];
    float m = -1e30f;
#pragma unroll
    for (int i = 0; i < 4; i++) {
        const int p = t + i * 256;
        v[i] = s1[b * PP + p];
        outStart[b * PP + p] = v[i];
        m = fmaxf(m, v[i]);
    }
#pragma unroll
    for (int off = 1; off < 64; off <<= 1) m = fmaxf(m, __shfl_xor(m, off));
    if ((t & 63) == 0) r4[t >> 6] = m;
    __syncthreads();
    m = fmaxf(fmaxf(r4[0], r4[1]), fmaxf(r4[2], r4[3]));
    float e[4];
    float s = 0.f;
#pragma unroll
    for (int i = 0; i < 4; i++) {
        e[i] = expf(v[i] - m);
        s += e[i];
    }
#pragma unroll
    for (int off = 1; off < 64; off <<= 1) s += __shfl_xor(s, off);
    if ((t & 63) == 0) r4b[t >> 6] = s;
    __syncthreads();
    s = r4b[0] + r4b[1] + r4b[2] + r4b[3];
    const float inv = 1.f / s;
#pragma unroll
    for (int i = 0; i < 4; i++) a1[b * PP + t + i * 256] = e[i] * inv;
}

// ---------------------------------------------------------------------------
// c[b][h] += sum_{p in seg} a1[b][p] * hp[p][b][h].  grid (HH/256, BB, 8)
// ---------------------------------------------------------------------------
__global__ __launch_bounds__(256) void weighted_pool_p(
    const float* __restrict__ hp, const float* __restrict__ a1,
    float* __restrict__ c) {
    const int b = blockIdx.y;
    const int h = blockIdx.x * 256 + threadIdx.x;
    const int ps = blockIdx.z;
    __shared__ float aw[128];
    if (threadIdx.x < 128) aw[threadIdx.x] = a1[b * PP + ps * 128 + threadIdx.x];
    __syncthreads();
    float acc = 0.f;
    const long base = ((long)ps * 128 * BB + b) * HH + h;
#pragma unroll 8
    for (int p = 0; p < 128; p++)
        acc += aw[p] * hp[base + (long)p * (BB * HH)];
    atomicAdd(&c[b * HH + h], acc);
}

// ---------------------------------------------------------------------------
// GRU gemms (MFMA split-bf16, reg-prefetch pipelined): gi = c @ W_ih^T,
// gh = ha0 @ W_hh^T.  (64 x 3072, K=1024).  grid (48, 2), 256 thr = 4 waves.
// ---------------------------------------------------------------------------
__global__ __launch_bounds__(256) void gru_gemm(
    const float* __restrict__ c, const float* __restrict__ ha0,
    const float* __restrict__ W_ih, const float* __restrict__ W_hh,
    float* __restrict__ gi, float* __restrict__ gh) {
    const float* X = blockIdx.y ? ha0 : c;
    const float* W = blockIdx.y ? W_hh : W_ih;
    float* out = blockIdx.y ? gh : gi;
    const int n0 = blockIdx.x * 64;

    __shared__ unsigned short Ah[64 * LDA], Al[64 * LDA];
    __shared__ unsigned short Bh[64 * LDA], Bl[64 * LDA];

    const int t = threadIdx.x;
    const int w = t >> 6;
    const int l = t & 63;
    const int lr = l & 15;
    const int lg = l >> 4;
    const int r0 = t >> 3, q0 = t & 7;            // slot 0: rows 0..31
    const int r1 = (t + 256) >> 3, q1 = t & 7;    // slot 1: rows 32..63

    f32x4 acc[4];
#pragma unroll
    for (int mt = 0; mt < 4; mt++) acc[mt] = (f32x4){0.f, 0.f, 0.f, 0.f};

    float4 xc0 = *reinterpret_cast<const float4*>(X + (size_t)r0 * 1024 + q0 * 4);
    float4 xc1 = *reinterpret_cast<const float4*>(X + (size_t)r1 * 1024 + q1 * 4);
    float4 wc0 = *reinterpret_cast<const float4*>(W + (size_t)(n0 + r0) * 1024 + q0 * 4);
    float4 wc1 = *reinterpret_cast<const float4*>(W + (size_t)(n0 + r1) * 1024 + q1 * 4);

    for (int k0 = 0; k0 < 1024; k0 += 32) {
        __syncthreads();
        split_store(Ah, Al, r0 * LDA + q0 * 4, xc0);
        split_store(Ah, Al, r1 * LDA + q1 * 4, xc1);
        split_store(Bh, Bl, r0 * LDA + q0 * 4, wc0);
        split_store(Bh, Bl, r1 * LDA + q1 * 4, wc1);
        float4 xn0 = xc0, xn1 = xc1, wn0 = wc0, wn1 = wc1;
        if (k0 + 32 < 1024) {
            const int kk = k0 + 32;
            xn0 = *reinterpret_cast<const float4*>(X + (size_t)r0 * 1024 + kk + q0 * 4);
            xn1 = *reinterpret_cast<const float4*>(X + (size_t)r1 * 1024 + kk + q1 * 4);
            wn0 = *reinterpret_cast<const float4*>(W + (size_t)(n0 + r0) * 1024 + kk + q0 * 4);
            wn1 = *reinterpret_cast<const float4*>(W + (size_t)(n0 + r1) * 1024 + kk + q1 * 4);
        }
        __syncthreads();

        const int br = (w * 16 + lr) * LDA + lg * 8;
        const ushort8 bh = *reinterpret_cast<const ushort8*>(&Bh[br]);
        const ushort8 bl = *reinterpret_cast<const ushort8*>(&Bl[br]);
#pragma unroll
        for (int mt = 0; mt < 4; mt++) {
            const int ar = (mt * 16 + lr) * LDA + lg * 8;
            const ushort8 ah = *reinterpret_cast<const ushort8*>(&Ah[ar]);
            const ushort8 al = *reinterpret_cast<const ushort8*>(&Al[ar]);
            acc[mt] = mfma16(ah, bh, acc[mt]);
            acc[mt] = mfma16(ah, bl, acc[mt]);
            acc[mt] = mfma16(al, bh, acc[mt]);
        }
        xc0 = xn0; xc1 = xn1; wc0 = wn0; wc1 = wn1;
    }

#pragma unroll
    for (int mt = 0; mt < 4; mt++)
#pragma unroll
        for (int r = 0; r < 4; r++) {
            const int row = mt * 16 + lg * 4 + r;
            const int n = n0 + w * 16 + lr;
            out[(size_t)row * H3 + n] = acc[mt][r];
        }
}

// ---------------------------------------------------------------------------
// Fused GRU gate + haW1: ha1 = GRU(c, ha0); haW1[b][a] = ha1 . Wha[a].
// torch GRUCell order [r, z, n], no bias.  grid (BB), 512 thr.
// ---------------------------------------------------------------------------
__global__ __launch_bounds__(512) void gate_haw(
    const float* __restrict__ gi, const float* __restrict__ gh,
    const float* __restrict__ ha0, const float* __restrict__ Wha,
    float* __restrict__ haW1) {
    const int b = blockIdx.x, t = threadIdx.x;
    __shared__ float hs[HH];
#pragma unroll
    for (int j = 0; j < 2; j++) {
        const int hn = t + j * 512;
        const size_t o = (size_t)b * H3 + hn;
        const float r = 1.f / (1.f + expf(-(gi[o] + gh[o])));
        const float z = 1.f / (1.f + expf(-(gi[o + 1024] + gh[o + 1024])));
        const float n = tanhf(gi[o + 2048] + r * gh[o + 2048]);
        hs[hn] = (1.f - z) * n + z * ha0[b * HH + hn];
    }
    __syncthreads();
    const int w8 = t >> 6, l = t & 63;
    for (int a = w8; a < AA; a += 8) {
        float s = 0.f;
#pragma unroll
        for (int j = 0; j < 16; j++)
            s += hs[l + 64 * j] * Wha[(size_t)a * HH + l + 64 * j];
#pragma unroll
        for (int off = 1; off < 64; off <<= 1) s += __shfl_xor(s, off);
        if (l == 0) haW1[b * APAD + a] = s;
    }
}

// ---------------------------------------------------------------------------
// end logits: s2[p][b] = sum_a tanh(Wh[r][a] + haW1[b][a]) * vw[a]
// ---------------------------------------------------------------------------
__global__ __launch_bounds__(256) void end_logits_k(
    const float* __restrict__ wh, const float* __restrict__ haW1,
    const float* __restrict__ vw, float* __restrict__ out) {
    const int row0 = blockIdx.x * 64;
    const int t = threadIdx.x;
    const int l = t & 15;
    const int rbase = (t >> 4) * 4;
#pragma unroll
    for (int i = 0; i < 4; i++) {
        const int r = row0 + rbase + i;
        const int b = r & 63;
        float partial = 0.f;
#pragma unroll
        for (int j = 0; j < 5; j++) {
            const int col = l + 16 * j;
            if (col < AA)
                partial +=
                    vw[col] * tanhf(wh[(size_t)r * APAD + col] + haW1[b * APAD + col]);
        }
        partial += __shfl_xor(partial, 1);
        partial += __shfl_xor(partial, 2);
        partial += __shfl_xor(partial, 4);
        partial += __shfl_xor(partial, 8);
        if (l == 0) {
            const int p = r >> 6;
            out[(size_t)BB * PP + b * PP + p] = partial;
        }
    }
}

extern "C" void kernel_launch(void* const* d_in, const int* in_sizes, int n_in,
                              void* d_out, int out_size, void* d_ws,
                              size_t ws_size, hipStream_t stream) {
    const float* hp   = (const float*)d_in[0];  // (P,B,HP)
    const float* u    = (const float*)d_in[1];  // (Q,B,HQ)
    const float* Whp  = (const float*)d_in[2];  // (A,HP)
    const float* Wha  = (const float*)d_in[3];  // (A,HQ)
    const float* v_w  = (const float*)d_in[4];  // (1,A)
    const float* Wuq  = (const float*)d_in[5];  // (A,HQ)
    const float* v1w  = (const float*)d_in[6];  // (1,A)
    const float* v1b  = (const float*)d_in[7];  // (1,)
    const float* W_ih = (const float*)d_in[8];  // (3H,HP)
    const float* W_hh = (const float*)d_in[9];  // (3H,HQ)
    float* out = (float*)d_out;
    float* ws = (float*)d_ws;
    unsigned short* wsp_hp = (unsigned short*)(ws + OFF_GI);
    unsigned short* wsp_uq = (unsigned short*)(ws + OFF_GH);

    // 0. pre-split Whp / Wuq into bf16 hi/lo (DMA-linear tiled layout)
    hipLaunchKernelGGL(split_w, dim3(80), dim3(256), 0, stream, Whp, wsp_hp);
    hipLaunchKernelGGL(split_w, dim3(80), dim3(256), 0, stream, Wuq, wsp_uq);
    // 1. sq[b][q] = tanh(U @ Wuq^T) @ v1 + b1   (M = Q*B = 8192)
    hipLaunchKernelGGL((gemm_attn<false, false, true>), dim3(QQ * BB / BM),
                       dim3(256), 0, stream, u, wsp_uq, nullptr, v1w, v1b,
                       nullptr, ws + OFF_SQ, QQ);
    // 2-4. fused: softmax_q + ha0 pool + haW0 = ha0 @ Wha^T
    hipLaunchKernelGGL(init_state, dim3(BB), dim3(512), 0, stream, u,
                       ws + OFF_SQ, Wha, ws + OFF_HA0, ws + OFF_HAW0);
    // 5. Wh GEMM + s1 epilogue (M = P*B = 65536), stores raw Wh
    hipLaunchKernelGGL((gemm_attn<true, true, false>), dim3(PP * BB / BM),
                       dim3(256), 0, stream, hp, wsp_hp, ws + OFF_HAW0, v_w,
                       nullptr, ws + OFF_WH, ws + OFF_S1, PP);
    // 6. softmax over p + start logits
    hipLaunchKernelGGL(softmax_p, dim3(BB), dim3(256), 0, stream, ws + OFF_S1,
                       ws + OFF_A1, out);
    // 7. c = sum_p a1 * h_passage  (zero + atomic partial sums)
    hipMemsetAsync(ws + OFF_C, 0, (size_t)BB * HH * sizeof(float), stream);
    hipLaunchKernelGGL(weighted_pool_p, dim3(HH / 256, BB, 8), dim3(256), 0,
                       stream, hp, ws + OFF_A1, ws + OFF_C);
    // 8. GRU gemms (overwrites gi/gh: pre-split weights dead by now)
    hipLaunchKernelGGL(gru_gemm, dim3(H3 / 64, 2), dim3(256), 0, stream,
                       ws + OFF_C, ws + OFF_HA0, W_ih, W_hh, ws + OFF_GI,
                       ws + OFF_GH);
    // 9. fused gate + haW1
    hipLaunchKernelGGL(gate_haw, dim3(BB), dim3(512), 0, stream, ws + OFF_GI,
                       ws + OFF_GH, ws + OFF_HA0, Wha, ws + OFF_HAW1);
    // 10. end logits from stored Wh
    hipLaunchKernelGGL(end_logits_k, dim3(PP * BB / 64), dim3(256), 0, stream,
                       ws + OFF_WH, ws + OFF_HAW1, v_w, out);
    (void)in_sizes; (void)n_in; (void)out_size; (void)ws_size;
}